// Round 10
// baseline (227.657 us; speedup 1.0000x reference)
//
#include <hip/hip_runtime.h>
#include <hip/hip_bf16.h>
#include <stdint.h>

#define E_ 768
#define H_ 768
#define C_ 9
#define M_TOTAL 32768
#define BM_ 64           // tokens per block (R11: back to 64 — R10 proved B traffic must not grow)

typedef __attribute__((ext_vector_type(8))) __bf16 bf16x8;
typedef __attribute__((ext_vector_type(4))) float f32x4;
typedef __attribute__((ext_vector_type(4))) int i32x4;

#define GLOBAL_AS __attribute__((address_space(1)))
#define LDS_AS    __attribute__((address_space(3)))

static_assert(sizeof(bf16x8) == 16, "bf16x8 must be 16B");

__device__ __forceinline__ unsigned short f2bf(float f) {
    __hip_bfloat16 h = __float2bfloat16(f);
    return __builtin_bit_cast(unsigned short, h);
}

// ---------------------------------------------------------------------------
// Prep (unchanged): W1 -> bf16 B-fragment cells, ntile-major; W2 -> padded
// B-frag cells; loss zeroed.
//   W1f[((ntile*24 + t)*64 + lane)*8 + j] = bf16(W1[k][n])
//     ntile=n>>4, t=k>>5, lane=(n&15)+16*((k>>3)&3), j=k&7
// ---------------------------------------------------------------------------
__global__ void prep_kernel(const float* __restrict__ W1, const float* __restrict__ W2,
                            unsigned short* __restrict__ W1f, unsigned short* __restrict__ W2f,
                            float* __restrict__ loss_out)
{
    int b = blockIdx.x;
    int n = threadIdx.x;
    if (b < 768) {
        int k = b;
        float v = W1[k * H_ + n];
        int ntile = n >> 4;
        int t = k >> 5;
        int lane = (n & 15) + 16 * ((k >> 3) & 3);
        int j = k & 7;
        W1f[((ntile * 24 + t) * 64 + lane) * 8 + j] = f2bf(v);
    } else {
        for (int it = 0; it < 16; ++it) {
            int tid = it * 768 + n;
            int j    = tid & 7;
            int lane = (tid >> 3) & 63;
            int t    = tid >> 9;
            int cls  = lane & 15;
            int k = t * 32 + (lane >> 4) * 8 + j;
            W2f[tid] = (cls < C_) ? f2bf(W2[k * C_ + cls]) : (unsigned short)0;
        }
        if (n == 0) *loss_out = 0.0f;
    }
}

// ---------------------------------------------------------------------------
// Fused head kernel, round 11: B through LDS via global_load_lds + counted
// vmcnt (T3/T4). R10's A/B proved the W1f L2->CU path is serialized into the
// critical path, and VGPR_Count=64 proved the compiler COLLAPSED the register
// B-prefetch (needs ~110 regs, got 64) into just-in-time loads -> per-k-step
// L2 latency exposure = the persistent ~44% unaccounted time.
// global_load_lds has NO destination VGPR -> the compiler cannot shrink the
// prefetch distance. Each wave self-stages its 3 ntile cells (1KB each) for
// k-step k+1 during k (dbuf 2x48KB, cells private per wave -> no races, no
// barrier needed for B), waits counted vmcnt (never 0 mid-loop), ds_read_b128
// frags (lane*16B linear = conflict-free). A path unchanged from R9 (chunk
// dbuf + af register dbuf). LDS = 96KB B + 32KB A = 128KB, 1 block/CU,
// 16 waves. Barriers remain lgkm-only (A visibility); B DMAs fly across them.
// vmcnt schedule (derived from fixed issue order, rg pinned by "" barrier):
//   tl=0 & c<5 -> vmcnt(5) [rg2 + B(k+1)3 younger]; k=23 -> vmcnt(0);
//   else vmcnt(3) [B(k+1)3 younger].
// ---------------------------------------------------------------------------
__launch_bounds__(1024, 4)
__global__ void fused_head_kernel(const float* __restrict__ hidden,
                                  const unsigned short* __restrict__ W1f,
                                  const float* __restrict__ b1,
                                  const unsigned short* __restrict__ W2f,
                                  const float* __restrict__ b2,
                                  const int* __restrict__ labels,
                                  const int* __restrict__ epoch_p,
                                  float* __restrict__ probs,
                                  float* __restrict__ loss)
{
    __shared__ unsigned short L[65536];   // 128 KB: B dbuf [0,24576),[24576,49152); A dbuf [49152,57344),[57344,65536)

    const int tid  = threadIdx.x;
    const int w    = tid >> 6;     // wave 0..15
    const int lane = tid & 63;
    const int tok0 = blockIdx.x * BM_;
    const int c16  = lane & 15;
    const int q    = lane >> 4;

    // ---- A staging geometry (as R9): thread handles rows tkA, tkA+32 ----
    const f32x4* hsrc = (const f32x4*)(hidden + (size_t)tok0 * E_);
    const int tkA = tid >> 5;        // 0..31
    const int fq  = tid & 31;
    const int t_l = fq >> 3;
    const int jj  = (fq & 1) * 4;
    const int q2s = (fq >> 1) & 3;

    f32x4 rg0, rg1;
    auto issue = [&](int c) {
        rg0 = __builtin_nontemporal_load(hsrc + (size_t)tkA * 192 + c * 32 + fq);
        rg1 = __builtin_nontemporal_load(hsrc + (size_t)(tkA + 32) * 192 + c * 32 + fq);
    };
    auto stage = [&](int bsel) {
        unsigned short* bufp = &L[49152 + bsel * 8192];
        {
            int lnf = (tkA & 15) + 16 * q2s;
            int mt  = tkA >> 4;
            ushort4 pk = { f2bf(rg0[0]), f2bf(rg0[1]), f2bf(rg0[2]), f2bf(rg0[3]) };
            *(ushort4*)(&bufp[((t_l * 4 + mt) * 64 + lnf) * 8 + jj]) = pk;
        }
        {
            int tk = tkA + 32;
            int lnf = (tk & 15) + 16 * q2s;
            int mt  = tk >> 4;
            ushort4 pk = { f2bf(rg1[0]), f2bf(rg1[1]), f2bf(rg1[2]), f2bf(rg1[3]) };
            *(ushort4*)(&bufp[((t_l * 4 + mt) * 64 + lnf) * 8 + jj]) = pk;
        }
    };

    // ---- B self-staging: wave w DMAs its cells (w*3..w*3+2) for k-step kk ----
    // LDS dest is wave-uniform base; HW writes lane's 16B at base+lane*16.
    // Global source is per-lane: cell is 1KB contiguous, lane reads cell+16*lane.
    auto issueB = [&](int kk) {
        const int bb = (kk & 1) * 24576;
        #pragma unroll
        for (int i = 0; i < 3; ++i) {
            const int cell = w * 3 + i;
            const unsigned short* g = W1f + ((size_t)(cell * 24 + kk) * 64 + lane) * 8;
            __builtin_amdgcn_global_load_lds((const GLOBAL_AS void*)g,
                                             (LDS_AS void*)&L[bb + cell * 512],
                                             16, 0, 0);
        }
    };

    // ---- prologue: A chunk0 + B(0) in flight ----
    issue(0);
    issueB(0);
    asm volatile("" ::: "memory");   // pin issue order: rg before later B issues

    const f32x4 zero4 = {0.0f, 0.0f, 0.0f, 0.0f};
    f32x4 acc[4][3];
    #pragma unroll
    for (int mt = 0; mt < 4; ++mt)
        #pragma unroll
        for (int nt = 0; nt < 3; ++nt) acc[mt][nt] = zero4;

    stage(0);                        // compiler waits rg (vmcnt leaves B(0) in flight)
    asm volatile("s_waitcnt lgkmcnt(0)\ns_barrier" ::: "memory");

    // ---- af register double-buffer, prologue step 0 ----
    bf16x8 af[2][4];
    {
        const unsigned short* abuf = &L[49152];
        #pragma unroll
        for (int mt = 0; mt < 4; ++mt)
            af[0][mt] = __builtin_bit_cast(bf16x8,
                *(const i32x4*)(&abuf[((0 * 4 + mt) * 64 + lane) * 8]));
    }

    // ---- K loop: 6 chunks x 4 k-steps; B dist-1 self-staged via LDS ----
    #pragma unroll
    for (int c = 0; c < 6; ++c) {
        const unsigned short* abuf = &L[49152 + (c & 1) * 8192];
        if (c < 5) issue(c + 1);
        asm volatile("" ::: "memory");   // pin rg issue before this chunk's B issues
        #pragma unroll
        for (int tl = 0; tl < 4; ++tl) {
            const int k = 4 * c + tl;    // global k-step 0..23
            const int cur = tl & 1;
            if (k + 1 < 24) issueB(k + 1);
            // wait until B(k)'s 3 DMAs are complete (counted, never drain mid-loop)
            if (tl == 0 && c < 5)      asm volatile("s_waitcnt vmcnt(5)" ::: "memory");
            else if (k == 23)          asm volatile("s_waitcnt vmcnt(0)" ::: "memory");
            else                       asm volatile("s_waitcnt vmcnt(3)" ::: "memory");
            // B fragments from LDS (lane*16B linear -> conflict-free)
            bf16x8 bf[3];
            {
                const unsigned short* bbuf = &L[(k & 1) * 24576];
                #pragma unroll
                for (int i = 0; i < 3; ++i)
                    bf[i] = __builtin_bit_cast(bf16x8,
                        *(const i32x4*)(&bbuf[(w * 3 + i) * 512 + lane * 8]));
            }
            // prefetch next step's A frags
            if (tl < 3) {
                #pragma unroll
                for (int mt = 0; mt < 4; ++mt)
                    af[cur ^ 1][mt] = __builtin_bit_cast(bf16x8,
                        *(const i32x4*)(&abuf[(((tl + 1) * 4 + mt) * 64 + lane) * 8]));
            }
            __builtin_amdgcn_s_setprio(1);
            #pragma unroll
            for (int mt = 0; mt < 4; ++mt)
                #pragma unroll
                for (int nt = 0; nt < 3; ++nt)
                    acc[mt][nt] = __builtin_amdgcn_mfma_f32_16x16x32_bf16(
                        af[cur][mt], bf[nt], acc[mt][nt], 0, 0, 0);
            __builtin_amdgcn_s_setprio(0);
            if (tl == 1 && c < 5) stage((c + 1) & 1);
        }
        // lgkm-only barrier: A buffer visibility; B DMAs stay in flight
        asm volatile("s_waitcnt lgkmcnt(0)\ns_barrier" ::: "memory");
        if (c < 5) {
            const unsigned short* abn = &L[49152 + ((c + 1) & 1) * 8192];
            #pragma unroll
            for (int mt = 0; mt < 4; ++mt)
                af[0][mt] = __builtin_bit_cast(bf16x8,
                    *(const i32x4*)(&abn[((0 * 4 + mt) * 64 + lane) * 8]));
        }
    }

    // ---- epilogue: all 16 waves write tanh into Hsh = L[0..49152) ----
    unsigned short* Hsh = &L[0];
    #pragma unroll
    for (int i = 0; i < 3; ++i) {
        int col = w * 48 + i * 16 + c16;        // global h-column 0..767
        float b1b = b1[col];
        int t2 = col >> 5;
        int q2 = (col >> 3) & 3;
        int j  = col & 7;
        #pragma unroll
        for (int mt = 0; mt < 4; ++mt) {
            #pragma unroll
            for (int r = 0; r < 4; ++r) {
                float z = acc[mt][i][r] + b1b;
                // tanh(z) = 1 - 2/(exp(2z)+1), exp via native exp2
                float e = exp2f(z * 2.8853900817779268f);
                float th = 1.0f - 2.0f * __builtin_amdgcn_rcpf(e + 1.0f);
                int lanep = (q * 4 + r) + 16 * q2;
                Hsh[((t2 * 4 + mt) * 64 + lanep) * 8 + j] = f2bf(th);
            }
        }
    }
    asm volatile("s_waitcnt lgkmcnt(0)\ns_barrier" ::: "memory");

    // ---- logit GEMM (24 straight k-steps, waves 0-3) + softmax + loss ----
    if (w < 4) {
        f32x4 logit = zero4;
        #pragma unroll
        for (int t2 = 0; t2 < 24; ++t2) {
            bf16x8 ha = __builtin_bit_cast(bf16x8, *(const i32x4*)(&Hsh[((t2 * 4 + w) * 64 + lane) * 8]));
            bf16x8 wb = __builtin_bit_cast(bf16x8, *(const i32x4*)(W2f + ((size_t)t2 * 64 + lane) * 8));
            logit = __builtin_amdgcn_mfma_f32_16x16x32_bf16(ha, wb, logit, 0, 0, 0);
        }

        const bool valid = (c16 < C_);
        const float b2v = valid ? b2[c16] : 0.0f;
        const int ep = epoch_p[0];
        float lsum = 0.0f;
        #pragma unroll
        for (int r = 0; r < 4; ++r) {
            float l = valid ? (logit[r] + b2v) : -3.0e38f;
            float m = l;
            #pragma unroll
            for (int d = 1; d < 16; d <<= 1)
                m = fmaxf(m, __shfl_xor(m, d, 64));
            float e = valid ? exp2f((l - m) * 1.44269504f) : 0.0f;
            float s = e;
            #pragma unroll
            for (int d = 1; d < 16; d <<= 1)
                s += __shfl_xor(s, d, 64);
            float p = e / s;
            int row = tok0 + w * 16 + q * 4 + r;
            if (valid) __builtin_nontemporal_store(p, &probs[(size_t)row * C_ + c16]);
            int lab = labels[row];
            if (valid && lab == c16) {
                float wgt = (ep <= 2) ? 1.0f : ((p > 0.7f) ? 1.0f : 0.0f);
                if (wgt > 0.0f)
                    lsum += (1.0f - exp2f(0.7f * log2f(p))) * (1.0f / 0.7f);
            }
        }
        #pragma unroll
        for (int d = 1; d < 64; d <<= 1)
            lsum += __shfl_xor(lsum, d, 64);
        if (lane == 0) atomicAdd(loss, lsum);
    }
}

// ---------------------------------------------------------------------------
extern "C" void kernel_launch(void* const* d_in, const int* in_sizes, int n_in,
                              void* d_out, int out_size, void* d_ws, size_t ws_size,
                              hipStream_t stream)
{
    const float* hidden = (const float*)d_in[0];
    const float* W1     = (const float*)d_in[1];
    const float* b1     = (const float*)d_in[2];
    const float* W2     = (const float*)d_in[3];
    const float* b2     = (const float*)d_in[4];
    const int*   labels = (const int*)d_in[5];
    const int*   epoch  = (const int*)d_in[6];

    float* probs = (float*)d_out;                       // [32768 x 9]
    float* loss  = probs + (size_t)M_TOTAL * C_;        // scalar at the end

    unsigned short* W1f = (unsigned short*)d_ws;        // 589824 bf16 (ntile-major)
    unsigned short* W2f = W1f + 48 * 24 * 512;          // 12288 bf16

    prep_kernel<<<769, 768, 0, stream>>>(W1, W2, W1f, W2f, loss);
    fused_head_kernel<<<M_TOTAL / BM_, 1024, 0, stream>>>(hidden, W1f, b1, W2f, b2,
                                                          labels, epoch, probs, loss);
}